// Round 1
// baseline (534.033 us; speedup 1.0000x reference)
//
#include <hip/hip_runtime.h>
#include <math.h>

// B=32, S=1024, D=512, F=8, KN=32 knots, H=8, hd=64. M = B*S = 32768 rows.

#define SOFF_AMEAN 0
#define SOFF_ARSTD 512
#define SOFF_OMEAN 1024
#define SOFF_ORSTD 1536
#define SOFF_PMEAN 2048
#define SOFF_PRSTD 2056
#define SOFF_FMIN  2064
#define SOFF_FMAX  2072
#define SOFF_SMEAN 2080
#define SOFF_SRSTD 3104
#define SOFF_G1    4128
#define SOFF_GB    4136
#define SOFF_SGB   4144
#define SOFF_QGB   4145
#define SOFF_G2    4160
#define SOFF_PART  4224

typedef short bf16x8_t __attribute__((ext_vector_type(8)));
typedef float f32x4_t __attribute__((ext_vector_type(4)));
typedef unsigned short us8_t __attribute__((ext_vector_type(8)));

__device__ __forceinline__ unsigned short f2bf(float f) {
  unsigned u = __float_as_uint(f);
  u = (u + 0x7FFFu + ((u >> 16) & 1u)) >> 16;
  return (unsigned short)u;
}
__device__ __forceinline__ float b2f(unsigned short u) {
  return __uint_as_float(((unsigned)u) << 16);
}

// compile-time-only reordering fence around raw s_barrier (NO waitcnt drain)
#define BARR do { asm volatile("" ::: "memory"); __builtin_amdgcn_s_barrier(); asm volatile("" ::: "memory"); } while (0)

// ---------------------------------------------------------------- zero scratch
__global__ __launch_bounds__(256) void zero_kernel(float* __restrict__ p) {
  p[blockIdx.x * 256 + threadIdx.x] = 0.f;
}

// ---------------------------------------------------------------- fp32 -> bf16
__global__ __launch_bounds__(256) void cvt8_kernel(const float* __restrict__ src,
                                                   unsigned short* __restrict__ dst) {
  int i = blockIdx.x * 256 + threadIdx.x;
  float4 a = ((const float4*)src)[i * 2];
  float4 b = ((const float4*)src)[i * 2 + 1];
  us8_t o;
  o[0] = f2bf(a.x); o[1] = f2bf(a.y); o[2] = f2bf(a.z); o[3] = f2bf(a.w);
  o[4] = f2bf(b.x); o[5] = f2bf(b.y); o[6] = f2bf(b.z); o[7] = f2bf(b.w);
  *(us8_t*)(dst + (size_t)i * 8) = o;
}

// ------------------------------------------------- bf16 MFMA GEMM  C = A@B^T + bias
// 256x256 tile, BK=64, 8 waves (2Mx4N), 8-phase-style schedule (T2 swizzle + T3
// stage-early/drain-late + T5 setprio). LDS = 128 KiB 2-side double buffer.
// XOR-swizzle (chunk ^= row&7) applied on global SOURCE (LDS dest linear, as
// global_load_lds requires) and identically on the ds_read side -> conflict-free.
// STATS: per-column sum/sumsq reduced via shfl, then direct global atomics.
template<int NT, bool OUT_BF16, bool STATS>
__global__ __launch_bounds__(512, 2) void gemm256_kernel(
    const unsigned short* __restrict__ A, const unsigned short* __restrict__ B,
    const float* __restrict__ bias, unsigned short* __restrict__ Cb,
    float* __restrict__ Cf, float* __restrict__ gstats, int N) {
  __shared__ unsigned short As[2][256 * 64];
  __shared__ unsigned short Bs[2][256 * 64];
  const int bi = blockIdx.x;
  const int xcd = bi & 7, jb = bi >> 3;          // 128 M-tiles: 16 per XCD
  const int m0 = (xcd * 16 + jb / NT) * 256;
  const int n0 = (jb % NT) * 256;
  const int t = threadIdx.x;
  const int w = t >> 6, lane = t & 63;
  const int wm = w >> 2, wn = w & 3;             // 2 x 4 wave grid

  // staging geometry: per gload, wave covers 8 rows x 8 chunks of 16B
  const int srow = lane >> 3;                    // 0..7 row within 8-row slab
  const int sgo = ((lane & 7) ^ srow) * 8;       // swizzled source chunk (elements)
  const unsigned short* gA = A + (size_t)(m0 + w * 32 + srow) * 512 + sgo;
  const unsigned short* gB = B + (size_t)(n0 + w * 32 + srow) * 512 + sgo;

  // fragment read geometry
  const int fr = lane & 15, g = lane >> 4;
  const int swz = fr & 7;                        // XOR key (row&7)

  f32x4_t acc[8][4];
#pragma unroll
  for (int i = 0; i < 8; ++i)
#pragma unroll
    for (int jj = 0; jj < 4; ++jj) acc[i][jj] = (f32x4_t){0.f, 0.f, 0.f, 0.f};

#define STAGE(SX, KO) do { \
  _Pragma("unroll") for (int jj = 0; jj < 4; ++jj) { \
    __builtin_amdgcn_global_load_lds( \
        (const __attribute__((address_space(1))) void*)(gA + (size_t)jj * 8 * 512 + (KO)), \
        (__attribute__((address_space(3))) void*)&As[SX][(w * 32 + jj * 8) * 64], 16, 0, 0); \
    __builtin_amdgcn_global_load_lds( \
        (const __attribute__((address_space(1))) void*)(gB + (size_t)jj * 8 * 512 + (KO)), \
        (__attribute__((address_space(3))) void*)&Bs[SX][(w * 32 + jj * 8) * 64], 16, 0, 0); \
  } \
} while (0)

#define RDA(MI0) do { \
  _Pragma("unroll") for (int m2 = 0; m2 < 2; ++m2) \
    _Pragma("unroll") for (int ks = 0; ks < 2; ++ks) \
      af[m2][ks] = *(const bf16x8_t*)&as[((wm * 128 + (MI0 + m2) * 16 + fr) * 64) + (((ks * 4 + g) ^ swz) * 8)]; \
} while (0)

#define QUAD(MI0) do { \
  __builtin_amdgcn_s_setprio(1); \
  _Pragma("unroll") for (int ks = 0; ks < 2; ++ks) \
    _Pragma("unroll") for (int m2 = 0; m2 < 2; ++m2) \
      _Pragma("unroll") for (int ni = 0; ni < 4; ++ni) \
        acc[MI0 + m2][ni] = __builtin_amdgcn_mfma_f32_16x16x32_bf16(af[m2][ks], bfr[ni][ks], acc[MI0 + m2][ni], 0, 0, 0); \
  __builtin_amdgcn_s_setprio(0); \
} while (0)

  // prologue: stage K-tile 0 into side 0, full drain once
  STAGE(0, (size_t)0);
  asm volatile("s_waitcnt vmcnt(0)" ::: "memory");
  BARR;

#pragma unroll 2
  for (int kt = 0; kt < 8; ++kt) {
    const int sd = kt & 1;
    const unsigned short* as = &As[sd][0];
    const unsigned short* bs = &Bs[sd][0];
    bf16x8_t bfr[4][2], af[2][2];

    // ---- phase 0: B-frags (8 reads) + A quad 0 (4 reads), issue next-tile stage
#pragma unroll
    for (int ni = 0; ni < 4; ++ni)
#pragma unroll
      for (int ks = 0; ks < 2; ++ks)
        bfr[ni][ks] = *(const bf16x8_t*)&bs[((wn * 64 + ni * 16 + fr) * 64) + (((ks * 4 + g) ^ swz) * 8)];
    RDA(0);
    if (kt < 7) STAGE(sd ^ 1, (size_t)(kt + 1) * 64);   // ~4 phases of cover
    BARR;
    QUAD(0);
    BARR;
    // ---- phase 1
    RDA(2);
    BARR;
    QUAD(2);
    BARR;
    // ---- phase 2
    RDA(4);
    BARR;
    QUAD(4);
    BARR;
    // ---- phase 3: drain own next-tile loads late, then publish via barrier
    RDA(6);
    BARR;
    QUAD(6);
    if (kt < 7) asm volatile("s_waitcnt vmcnt(0)" ::: "memory");
    BARR;
  }

  // epilogue: C/D mapping col=lane&15, row=(lane>>4)*4+reg
  const int cr = (lane >> 4) * 4, cc = lane & 15;
#pragma unroll
  for (int ni = 0; ni < 4; ++ni) {
    int col = n0 + wn * 64 + ni * 16 + cc;
    float bv = bias[col];
    float lsum = 0.f, lsq = 0.f;
#pragma unroll
    for (int mi = 0; mi < 8; ++mi) {
#pragma unroll
      for (int jj = 0; jj < 4; ++jj) {
        int row = m0 + wm * 128 + mi * 16 + cr + jj;
        float v = acc[mi][ni][jj] + bv;
        if (OUT_BF16) Cb[(size_t)row * N + col] = f2bf(v);
        else          Cf[(size_t)row * N + col] = v;
        if (STATS) { lsum += v; lsq += v * v; }
      }
    }
    if (STATS) {
      lsum += __shfl_xor(lsum, 16); lsum += __shfl_xor(lsum, 32);
      lsq  += __shfl_xor(lsq, 16);  lsq  += __shfl_xor(lsq, 32);
      if (lane < 16) {                 // cc == lane here
        atomicAdd(&gstats[col], lsum);
        atomicAdd(&gstats[512 + col], lsq);
      }
    }
  }
#undef STAGE
#undef RDA
#undef QUAD
}

// ------------------------------------------ finalize column stats from atomic sums
__global__ __launch_bounds__(512) void statsfin_kernel(const float* __restrict__ part,
                                                       float* __restrict__ stats, int off) {
  int t = threadIdx.x;
  float mean = part[t] / 32768.f;
  float var = part[512 + t] / 32768.f - mean * mean;
  stats[off + t] = mean;
  stats[off + 512 + t] = rsqrtf(var + 1e-5f);
}

// ---------------------------------------------------------------- small attention
__global__ __launch_bounds__(256) void attn2_kernel(const unsigned short* __restrict__ qkv,
                                                    unsigned short* __restrict__ ctxb) {
  const int n = blockIdx.x, h = blockIdx.y, t = threadIdx.x;
  __shared__ float qs[32 * 68], ks[32 * 68], vs[32 * 68], ss[32 * 33];
  const int l = t >> 3, j0 = (t & 7) * 8;
  size_t rowb = ((size_t)(l * 1024 + n)) * 1536 + h * 64 + j0;
  us8_t qv = *(const us8_t*)(qkv + rowb);
  us8_t kv = *(const us8_t*)(qkv + rowb + 512);
  us8_t vv = *(const us8_t*)(qkv + rowb + 1024);
#pragma unroll
  for (int j = 0; j < 8; ++j) {
    qs[l * 68 + j0 + j] = b2f(qv[j]) * 0.125f;
    ks[l * 68 + j0 + j] = b2f(kv[j]);
    vs[l * 68 + j0 + j] = b2f(vv[j]);
  }
  __syncthreads();
  for (int o = t; o < 1024; o += 256) {
    int ll = o >> 5, m = o & 31;
    const float4* q4 = (const float4*)&qs[ll * 68];
    const float4* k4 = (const float4*)&ks[m * 68];
    float s = 0.f;
#pragma unroll
    for (int dd = 0; dd < 16; ++dd) {
      float4 a = q4[dd], b = k4[dd];
      s += a.x * b.x + a.y * b.y + a.z * b.z + a.w * b.w;
    }
    ss[ll * 33 + m] = s;
  }
  __syncthreads();
  if (t < 32) {
    float mx = -3e38f;
    for (int m = 0; m < 32; ++m) mx = fmaxf(mx, ss[t * 33 + m]);
    float sum = 0.f;
    for (int m = 0; m < 32; ++m) { float e = __expf(ss[t * 33 + m] - mx); ss[t * 33 + m] = e; sum += e; }
    float inv = 1.f / sum;
    for (int m = 0; m < 32; ++m) ss[t * 33 + m] *= inv;
  }
  __syncthreads();
  float o[8] = {0.f, 0.f, 0.f, 0.f, 0.f, 0.f, 0.f, 0.f};
#pragma unroll 8
  for (int m = 0; m < 32; ++m) {
    float pm = ss[l * 33 + m];
    const float* vr = &vs[m * 68 + j0];
#pragma unroll
    for (int j = 0; j < 8; ++j) o[j] += pm * vr[j];
  }
  us8_t ov;
#pragma unroll
  for (int j = 0; j < 8; ++j) ov[j] = f2bf(o[j]);
  *(us8_t*)(ctxb + ((size_t)(l * 1024 + n)) * 512 + h * 64 + j0) = ov;
}

// ---------------------------------------------------------------- projection (M x 8), fp32 x
__global__ __launch_bounds__(256) void proj_kernel(const float* __restrict__ x,
    const float* __restrict__ pw, const float* __restrict__ pb, float* __restrict__ p) {
  int blk = blockIdx.x, t = threadIdx.x;
  int r0 = blk * 64;
  __shared__ float xsp[64 * 33];
  __shared__ float pwc[8 * 33];
  int l = t >> 2, fg = t & 3;
  float acc0 = 0.f, acc1 = 0.f;
  for (int k0 = 0; k0 < 512; k0 += 32) {
    __syncthreads();
    for (int i = t; i < 2048; i += 256) { int ll = i >> 5, kk = i & 31; xsp[ll * 33 + kk] = x[(size_t)(r0 + ll) * 512 + k0 + kk]; }
    { int ff = t >> 5, kk = t & 31; pwc[ff * 33 + kk] = pw[ff * 512 + k0 + kk]; }
    __syncthreads();
#pragma unroll 8
    for (int kk = 0; kk < 32; ++kk) {
      float xv = xsp[l * 33 + kk];
      acc0 += xv * pwc[(fg * 2) * 33 + kk];
      acc1 += xv * pwc[(fg * 2 + 1) * 33 + kk];
    }
  }
  float2 o; o.x = acc0 + pb[fg * 2]; o.y = acc1 + pb[fg * 2 + 1];
  *(float2*)&p[(r0 + l) * 8 + fg * 2] = o;
}

// ---------------------------------------------------------------- proj BN stats (C=8)
__global__ __launch_bounds__(256) void projstats_kernel(const float* __restrict__ p,
                                                        float* __restrict__ part) {
  int t = threadIdx.x, blk = blockIdx.x;  // 64 blocks
  int f = t & 7;
  float s = 0.f, s2 = 0.f;
  for (int r = blk * 32 + (t >> 3); r < 32768; r += 2048) { float v = p[r * 8 + f]; s += v; s2 += v * v; }
  __shared__ float red[256], red2[256];
  red[t] = s; red2[t] = s2; __syncthreads();
  for (int off = 128; off >= 8; off >>= 1) { if (t < off) { red[t] += red[t + off]; red2[t] += red2[t + off]; } __syncthreads(); }
  if (t < 8) { part[blk * 16 + t] = red[t]; part[blk * 16 + 8 + t] = red2[t]; }
}
__global__ void projfin_kernel(const float* __restrict__ part, float* __restrict__ stats) {
  int t = threadIdx.x;
  if (t < 8) {
    float s = 0.f, s2 = 0.f;
    for (int b = 0; b < 64; ++b) { s += part[b * 16 + t]; s2 += part[b * 16 + 8 + t]; }
    float mean = s / 32768.f;
    float var = s2 / 32768.f - mean * mean;
    stats[SOFF_PMEAN + t] = mean;
    stats[SOFF_PRSTD + t] = rsqrtf(var + 1e-5f);
  }
}

// ------------------------------------------------- apply proj-BN in place + min/max
__global__ __launch_bounds__(256) void bnminmax_kernel(float* __restrict__ p,
    const float* __restrict__ stats, const float* __restrict__ png,
    const float* __restrict__ pnb, float* __restrict__ part) {
  int t = threadIdx.x, blk = blockIdx.x;  // 64 blocks
  int i0 = blk * 256 + t;
  int f = i0 & 7;
  float k1 = stats[SOFF_PRSTD + f] * png[f];
  float k0 = pnb[f] - stats[SOFF_PMEAN + f] * k1;
  float mn = 3e38f, mx = -3e38f;
  for (int i = i0; i < 262144; i += 16384) {
    float v = p[i] * k1 + k0;
    p[i] = v;
    mn = fminf(mn, v); mx = fmaxf(mx, v);
  }
  __shared__ float rmn[256], rmx[256];
  rmn[t] = mn; rmx[t] = mx; __syncthreads();
  for (int off = 128; off >= 8; off >>= 1) {
    if (t < off) { rmn[t] = fminf(rmn[t], rmn[t + off]); rmx[t] = fmaxf(rmx[t], rmx[t + off]); }
    __syncthreads();
  }
  if (t < 8) { part[blk * 16 + t] = rmn[t]; part[blk * 16 + 8 + t] = rmx[t]; }
}
__global__ void minmaxfin_kernel(const float* __restrict__ part, float* __restrict__ stats) {
  int t = threadIdx.x;
  if (t < 8) {
    float mn = 3e38f, mx = -3e38f;
    for (int b = 0; b < 64; ++b) { mn = fminf(mn, part[b * 16 + t]); mx = fmaxf(mx, part[b * 16 + 8 + t]); }
    stats[SOFF_FMIN + t] = mn;
    stats[SOFF_FMAX + t] = mx;
  }
}

// ---------------------------------------------------------------- spline (in place)
__global__ __launch_bounds__(256) void spline_kernel(float* __restrict__ p,
    const float* __restrict__ knots, const float* __restrict__ cps,
    const float* __restrict__ stats) {
  __shared__ float ksh[8 * 33], csh[8 * 33];
  int t = threadIdx.x;
  { int f = t >> 5, j = t & 31; ksh[f * 33 + j] = knots[t]; csh[f * 33 + j] = cps[t]; }
  __syncthreads();
  int i = blockIdx.x * 256 + t;
  int f = i & 7;
  float xv = p[i];
  float mn = stats[SOFF_FMIN + f], mx = stats[SOFF_FMAX + f];
  float xn = (xv - mn) / (mx - mn + 1e-6f);
  const float* kn = &ksh[f * 33];
  const float* cp = &csh[f * 33];
  int pcnt = 0;
#pragma unroll
  for (int j = 0; j < 32; ++j) pcnt += (kn[j] <= xn) ? 1 : 0;
  int idx = pcnt - 1;
  idx = idx < 0 ? 0 : (idx > 30 ? 30 : idx);
  float k0v = kn[idx], k1v = kn[idx + 1];
  float tt = (xn - k0v) / (k1v - k0v);
  float val = (1.f - tt) * cp[idx] + tt * cp[idx + 1];
  bool inr = (xn >= kn[0]) && (xn <= kn[31]);
  p[i] = inr ? val : 0.f;
}

// ------------------------------------------- gate-weight Grams (parallel, 88 blocks)
__global__ __launch_bounds__(256) void gateprep_kernel(const float* __restrict__ gw,
    const float* __restrict__ gb, float* __restrict__ stats) {
  int b = blockIdx.x, t = threadIdx.x;
  __shared__ float red[256];
  float s = 0.f;
  if (b < 64) {
    int f1 = b >> 3, f2 = b & 7;
    for (int j = t; j < 1024; j += 256) s += gw[j * 8 + f1] * gw[j * 8 + f2];
  } else if (b < 72) {
    int f = b - 64;
    for (int j = t; j < 1024; j += 256) s += gw[j * 8 + f];
  } else if (b < 80) {
    int f = b - 72;
    for (int j = t; j < 1024; j += 256) s += gb[j] * gw[j * 8 + f];
  } else if (b == 80) {
    for (int j = t; j < 1024; j += 256) s += gb[j];
  } else {
    for (int j = t; j < 1024; j += 256) s += gb[j] * gb[j];
  }
  red[t] = s; __syncthreads();
  for (int off = 128; off > 0; off >>= 1) { if (t < off) red[t] += red[t + off]; __syncthreads(); }
  if (t == 0) {
    float v = red[0];
    if (b < 64) stats[SOFF_G2 + b] = v;
    else if (b < 72) stats[SOFF_G1 + (b - 64)] = v;
    else if (b < 80) stats[SOFF_GB + (b - 72)] = v;
    else if (b == 80) stats[SOFF_SGB] = v;
    else stats[SOFF_QGB] = v;
  }
}

// -------------------------------------- per-s BN stats of h WITHOUT materializing h
__global__ __launch_bounds__(256) void sstats_kernel(const float* __restrict__ tbuf,
                                                     float* __restrict__ stats) {
  int s = blockIdx.x, t = threadIdx.x;
  __shared__ float tv[256];
  __shared__ float red[256];
  __shared__ float T1[8];
  __shared__ float Ms[64];
  int b = t >> 3, f = t & 7;
  tv[t] = tbuf[(b * 1024 + s) * 8 + f];
  __syncthreads();
  red[t] = tv[t]; __syncthreads();
  for (int off = 128; off >= 8; off >>= 1) { if (t < off) red[t] += red[t + off]; __syncthreads(); }
  if (t < 8) T1[t] = red[t];
  if (t < 64) {
    int f1 = t >> 3, f2 = t & 7; float sM = 0.f;
    for (int bb = 0; bb < 32; ++bb) sM += tv[bb * 8 + f1] * tv[bb * 8 + f2];
    Ms[t] = sM;
  }
  __syncthreads();
  if (t == 0) {
    float sh = 0.f, s2 = 0.f;
    for (int ff = 0; ff < 8; ++ff) {
      sh += stats[SOFF_G1 + ff] * T1[ff];
      s2 += 2.f * stats[SOFF_GB + ff] * T1[ff];
    }
    sh += 32.f * stats[SOFF_SGB];
    for (int i = 0; i < 64; ++i) s2 += Ms[i] * stats[SOFF_G2 + i];
    s2 += 32.f * stats[SOFF_QGB];
    float mean = sh / 32768.f;
    float var = s2 / 32768.f - mean * mean;
    stats[SOFF_SMEAN + s] = mean;
    stats[SOFF_SRSTD + s] = rsqrtf(var + 1e-5f);
  }
}

// ---- recompute h row (fp32 gate_w — MUST match sstats' weights), BN-s, GLU, LN
__global__ __launch_bounds__(256) void gluln_kernel(const float* __restrict__ tbuf,
    const float* __restrict__ gw, const float* __restrict__ gb,
    const float* __restrict__ stats, const float* __restrict__ gbng,
    const float* __restrict__ gbnb, const float* __restrict__ lng,
    const float* __restrict__ lnb, unsigned short* __restrict__ gatedb) {
  const int t = threadIdx.x, wave = t >> 6, lane = t & 63;
  for (int rr = 0; rr < 4; ++rr) {
    const int r = blockIdx.x * 16 + wave * 4 + rr;
    const int s = r & 1023;
    float4 tA = *(const float4*)&tbuf[r * 8];
    float4 tB = *(const float4*)&tbuf[r * 8 + 4];
    float smean = stats[SOFF_SMEAN + s], srstd = stats[SOFF_SRSTD + s];
    float k1 = srstd * gbng[s];
    float k0 = gbnb[s] - smean * k1;
    float g[8];
    float sum = 0.f, sq = 0.f;
#pragma unroll
    for (int i = 0; i < 8; ++i) {
      int c = i * 64 + lane;
      float4 wa0 = *(const float4*)&gw[c * 8];
      float4 wa1 = *(const float4*)&gw[c * 8 + 4];
      float4 wb0 = *(const float4*)&gw[(c + 512) * 8];
      float4 wb1 = *(const float4*)&gw[(c + 512) * 8 + 4];
      float ha = tA.x * wa0.x + tA.y * wa0.y + tA.z * wa0.z + tA.w * wa0.w
               + tB.x * wa1.x + tB.y * wa1.y + tB.z * wa1.z + tB.w * wa1.w + gb[c];
      float hb = tA.x * wb0.x + tA.y * wb0.y + tA.z * wb0.z + tA.w * wb0.w
               + tB.x * wb1.x + tB.y * wb1.y + tB.z * wb1.z + tB.w * wb1.w + gb[c + 512];
      ha = ha * k1 + k0;
      hb = hb * k1 + k0;
      float gv = ha / (1.f + __expf(-hb));
      g[i] = gv; sum += gv; sq += gv * gv;
    }
#pragma unroll
    for (int m = 32; m >= 1; m >>= 1) { sum += __shfl_xor(sum, m); sq += __shfl_xor(sq, m); }
    float mean = sum * (1.f / 512.f);
    float rstd = rsqrtf(sq * (1.f / 512.f) - mean * mean + 1e-5f);
#pragma unroll
    for (int i = 0; i < 8; ++i) {
      int c = i * 64 + lane;
      gatedb[(size_t)r * 512 + c] = f2bf((g[i] - mean) * rstd * lng[c] + lnb[c]);
    }
  }
}

// ---------------------------------------------------------------- final elementwise
__global__ __launch_bounds__(256) void final_kernel(const float* __restrict__ x,
    const float* __restrict__ attn, const float* __restrict__ outl,
    const float* __restrict__ stats, const float* __restrict__ ag,
    const float* __restrict__ ab, const float* __restrict__ og,
    const float* __restrict__ ob, float* __restrict__ y) {
  int idx = blockIdx.x * 256 + threadIdx.x;
  int c4 = (idx & 127) * 4;
  float4 xv = ((const float4*)x)[idx];
  float4 av = ((const float4*)attn)[idx];
  float4 ov = ((const float4*)outl)[idx];
  float4 am = *(const float4*)&stats[SOFF_AMEAN + c4];
  float4 ar = *(const float4*)&stats[SOFF_ARSTD + c4];
  float4 om = *(const float4*)&stats[SOFF_OMEAN + c4];
  float4 orr = *(const float4*)&stats[SOFF_ORSTD + c4];
  float4 g1 = *(const float4*)&ag[c4];
  float4 b1 = *(const float4*)&ab[c4];
  float4 g2 = *(const float4*)&og[c4];
  float4 b2 = *(const float4*)&ob[c4];
  float4 o;
  o.x = xv.x + (av.x - am.x) * ar.x * g1.x + b1.x + (ov.x - om.x) * orr.x * g2.x + b2.x;
  o.y = xv.y + (av.y - am.y) * ar.y * g1.y + b1.y + (ov.y - om.y) * orr.y * g2.y + b2.y;
  o.z = xv.z + (av.z - am.z) * ar.z * g1.z + b1.z + (ov.z - om.z) * orr.z * g2.z + b2.z;
  o.w = xv.w + (av.w - am.w) * ar.w * g1.w + b1.w + (ov.w - om.w) * orr.w * g2.w + b2.w;
  ((float4*)y)[idx] = o;
}

extern "C" void kernel_launch(void* const* d_in, const int* in_sizes, int n_in,
                              void* d_out, int out_size, void* d_ws, size_t ws_size,
                              hipStream_t stream) {
  (void)in_sizes; (void)n_in; (void)out_size; (void)ws_size;
  const float* x        = (const float*)d_in[0];
  const float* in_w     = (const float*)d_in[1];
  const float* in_b     = (const float*)d_in[2];
  const float* out_w    = (const float*)d_in[3];
  const float* out_b    = (const float*)d_in[4];
  const float* attn_g   = (const float*)d_in[5];
  const float* attn_bt  = (const float*)d_in[6];
  const float* proj_w   = (const float*)d_in[7];
  const float* proj_b   = (const float*)d_in[8];
  const float* pn_g     = (const float*)d_in[9];
  const float* pn_bt    = (const float*)d_in[10];
  const float* knots    = (const float*)d_in[11];
  const float* cps      = (const float*)d_in[12];
  const float* gate_w   = (const float*)d_in[13];
  const float* gate_b   = (const float*)d_in[14];
  const float* gbn_g    = (const float*)d_in[15];
  const float* gbn_bt   = (const float*)d_in[16];
  const float* ln_g     = (const float*)d_in[17];
  const float* ln_bt    = (const float*)d_in[18];
  const float* outp_w   = (const float*)d_in[19];
  const float* outp_b   = (const float*)d_in[20];
  const float* on_g     = (const float*)d_in[21];
  const float* on_bt    = (const float*)d_in[22];

  float* out = (float*)d_out;
  unsigned short* xb      = (unsigned short*)d_ws;      // 16777216
  unsigned short* qkv_b   = xb + 16777216;              // 50331648
  unsigned short* ctx_b   = qkv_b + 50331648;           // 16777216
  unsigned short* wqkv_b  = ctx_b + 16777216;           // 786432
  unsigned short* wout_b  = wqkv_b + 786432;            // 262144
  unsigned short* woutp_b = wout_b + 262144;            // 262144
  float* proj  = (float*)(woutp_b + 262144);            // 262144 floats
  float* stats = proj + 262144;
  float* part  = stats + SOFF_PART;                     // 4096 floats
  float* partA  = part;                                 // 1024 (atomic col stats attn)
  float* partO  = part + 1024;                          // 1024 (atomic col stats out)
  float* partP  = part + 2048;                          // 1024 (projstats partials)
  float* partMM = part + 3072;                          // 1024 (minmax partials)
  float* attnf = (float*)qkv_b;      // alias: qkv dead after attn2
  unsigned short* gated_b = xb;      // alias: xb dead after qkv GEMM

  zero_kernel<<<dim3(8), dim3(256), 0, stream>>>(part);   // partA+partO
  cvt8_kernel<<<dim3(8192), dim3(256), 0, stream>>>(x, xb);
  cvt8_kernel<<<dim3(384), dim3(256), 0, stream>>>(in_w, wqkv_b);
  cvt8_kernel<<<dim3(128), dim3(256), 0, stream>>>(out_w, wout_b);
  cvt8_kernel<<<dim3(128), dim3(256), 0, stream>>>(outp_w, woutp_b);
  // qkv = x @ in_w^T + in_b -> bf16   (128 m-tiles x 6 n-tiles = 768 blocks)
  gemm256_kernel<6, true, false><<<dim3(768), dim3(512), 0, stream>>>(
      xb, wqkv_b, in_b, qkv_b, nullptr, nullptr, 1536);
  attn2_kernel<<<dim3(1024, 8), dim3(256), 0, stream>>>(qkv_b, ctx_b);
  // attn_lin = ctx @ out_w^T + out_b -> fp32 (+ fused column stats)
  gemm256_kernel<2, false, true><<<dim3(256), dim3(512), 0, stream>>>(
      ctx_b, wout_b, out_b, nullptr, attnf, partA, 512);
  statsfin_kernel<<<dim3(1), dim3(512), 0, stream>>>(partA, stats, SOFF_AMEAN);
  proj_kernel<<<dim3(512), dim3(256), 0, stream>>>(x, proj_w, proj_b, proj);
  projstats_kernel<<<dim3(64), dim3(256), 0, stream>>>(proj, partP);
  projfin_kernel<<<dim3(1), dim3(64), 0, stream>>>(partP, stats);
  bnminmax_kernel<<<dim3(64), dim3(256), 0, stream>>>(proj, stats, pn_g, pn_bt, partMM);
  minmaxfin_kernel<<<dim3(1), dim3(64), 0, stream>>>(partMM, stats);
  spline_kernel<<<dim3(1024), dim3(256), 0, stream>>>(proj, knots, cps, stats);
  gateprep_kernel<<<dim3(88), dim3(256), 0, stream>>>(gate_w, gate_b, stats);
  sstats_kernel<<<dim3(1024), dim3(256), 0, stream>>>(proj, stats);
  gluln_kernel<<<dim3(2048), dim3(256), 0, stream>>>(proj, gate_w, gate_b, stats,
                                                     gbn_g, gbn_bt, ln_g, ln_bt, gated_b);
  // out = gated @ outp_w^T + outp_b -> fp32 (+ fused column stats)
  gemm256_kernel<2, false, true><<<dim3(256), dim3(512), 0, stream>>>(
      gated_b, woutp_b, outp_b, nullptr, out, partO, 512);
  statsfin_kernel<<<dim3(1), dim3(512), 0, stream>>>(partO, stats, SOFF_OMEAN);
  final_kernel<<<dim3(16384), dim3(256), 0, stream>>>(x, attnf, out, stats,
                                                      attn_g, attn_bt, on_g, on_bt, out);
}

// Round 2
// 522.476 us; speedup vs baseline: 1.0221x; 1.0221x over previous
//
#include <hip/hip_runtime.h>
#include <math.h>

// B=32, S=1024, D=512, F=8, KN=32 knots, H=8, hd=64. M = B*S = 32768 rows.

#define SOFF_AMEAN 0
#define SOFF_ARSTD 512
#define SOFF_OMEAN 1024
#define SOFF_ORSTD 1536
#define SOFF_PMEAN 2048
#define SOFF_PRSTD 2056
#define SOFF_FMIN  2064
#define SOFF_FMAX  2072
#define SOFF_SMEAN 2080
#define SOFF_SRSTD 3104
#define SOFF_G1    4128
#define SOFF_GB    4136
#define SOFF_SGB   4144
#define SOFF_QGB   4145
#define SOFF_G2    4160
#define SOFF_PART  4224

typedef short bf16x8_t __attribute__((ext_vector_type(8)));
typedef float f32x4_t __attribute__((ext_vector_type(4)));
typedef unsigned short us8_t __attribute__((ext_vector_type(8)));

__device__ __forceinline__ unsigned short f2bf(float f) {
  unsigned u = __float_as_uint(f);
  u = (u + 0x7FFFu + ((u >> 16) & 1u)) >> 16;
  return (unsigned short)u;
}
__device__ __forceinline__ float b2f(unsigned short u) {
  return __uint_as_float(((unsigned)u) << 16);
}

// compile-time-only reordering fence around raw s_barrier (NO waitcnt drain)
#define BARR do { asm volatile("" ::: "memory"); __builtin_amdgcn_s_barrier(); asm volatile("" ::: "memory"); } while (0)

// ---------------------------------------------------------------- zero scratch
__global__ __launch_bounds__(256) void zero_kernel(float* __restrict__ p) {
  p[blockIdx.x * 256 + threadIdx.x] = 0.f;
}

// ---------------------------------------------------------------- fp32 -> bf16
__global__ __launch_bounds__(256) void cvt8_kernel(const float* __restrict__ src,
                                                   unsigned short* __restrict__ dst) {
  int i = blockIdx.x * 256 + threadIdx.x;
  float4 a = ((const float4*)src)[i * 2];
  float4 b = ((const float4*)src)[i * 2 + 1];
  us8_t o;
  o[0] = f2bf(a.x); o[1] = f2bf(a.y); o[2] = f2bf(a.z); o[3] = f2bf(a.w);
  o[4] = f2bf(b.x); o[5] = f2bf(b.y); o[6] = f2bf(b.z); o[7] = f2bf(b.w);
  *(us8_t*)(dst + (size_t)i * 8) = o;
}

// ------------------------------------------------- bf16 MFMA GEMM  C = A@B^T + bias
// 256x256 tile, BK=32, 8 waves (2Mx4N). Quad-buffered ring (4 x 16KB x 2 ops =
// 128 KiB LDS), prefetch distance 3 tiles, COUNTED vmcnt(8) at tile boundaries
// (tiles t+2,t+3 = 8 loads always in flight; buffer t+1 proven resident by each
// wave's own vmcnt + barrier). One raw s_barrier per tile; waves free-run inside.
// XOR swizzle chunk ^= (row>>1)&3 on global SOURCE + identically on ds_read side
// (LDS dest linear as global_load_lds requires) -> max 2-way (free).
// Epilogue: row-burst store order (full 128B line per row written back-to-back).
// STATS: per-column sum/sumsq via shfl then global atomics.
template<int NT, bool OUT_BF16, bool STATS>
__global__ __launch_bounds__(512, 2) void gemm256_kernel(
    const unsigned short* __restrict__ A, const unsigned short* __restrict__ B,
    const float* __restrict__ bias, unsigned short* __restrict__ Cb,
    float* __restrict__ Cf, float* __restrict__ gstats, int N) {
  __shared__ unsigned short As[4][256 * 32];
  __shared__ unsigned short Bs[4][256 * 32];
  const int bi = blockIdx.x;
  const int xcd = bi & 7, jb = bi >> 3;          // 128 M-tiles: 16 per XCD
  const int m0 = (xcd * 16 + jb / NT) * 256;
  const int n0 = (jb % NT) * 256;
  const int t = threadIdx.x;
  const int w = t >> 6, lane = t & 63;
  const int wm = w >> 2, wn = w & 3;             // 2 x 4 wave grid

  // staging: per load, wave covers 16 rows x 4 chunks of 16B (lane-linear LDS).
  // source chunk pre-swizzled: c_src = (lane&3) ^ ((lane>>3)&3)  [= c_lds ^ key(row)]
  const unsigned short* gA = A + (size_t)(m0 + w * 16 + (lane >> 2)) * 512
                               + (((lane & 3) ^ ((lane >> 3) & 3)) * 8);
  const unsigned short* gB = B + (size_t)(n0 + w * 16 + (lane >> 2)) * 512
                               + (((lane & 3) ^ ((lane >> 3) & 3)) * 8);

  // fragment read geometry: key(row) = (row>>1)&3 = (fr>>1)&3 for all frag rows
  const int fr = lane & 15, g = lane >> 4;       // g in 0..3
  const int kf = (fr >> 1) & 3;

  f32x4_t acc[8][4];
#pragma unroll
  for (int i = 0; i < 8; ++i)
#pragma unroll
    for (int jj = 0; jj < 4; ++jj) acc[i][jj] = (f32x4_t){0.f, 0.f, 0.f, 0.f};

#define STAGE(KT) do { \
    __builtin_amdgcn_global_load_lds( \
        (const __attribute__((address_space(1))) void*)(gA + (KT) * 32), \
        (__attribute__((address_space(3))) void*)&As[(KT) & 3][(w * 16) * 32], 16, 0, 0); \
    __builtin_amdgcn_global_load_lds( \
        (const __attribute__((address_space(1))) void*)(gA + (KT) * 32 + 128 * 512), \
        (__attribute__((address_space(3))) void*)&As[(KT) & 3][(128 + w * 16) * 32], 16, 0, 0); \
    __builtin_amdgcn_global_load_lds( \
        (const __attribute__((address_space(1))) void*)(gB + (KT) * 32), \
        (__attribute__((address_space(3))) void*)&Bs[(KT) & 3][(w * 16) * 32], 16, 0, 0); \
    __builtin_amdgcn_global_load_lds( \
        (const __attribute__((address_space(1))) void*)(gB + (KT) * 32 + 128 * 512), \
        (__attribute__((address_space(3))) void*)&Bs[(KT) & 3][(128 + w * 16) * 32], 16, 0, 0); \
  } while (0)

  // prologue: stage tiles 0,1,2; wait tile-0 (8 newest stay in flight); publish
  STAGE(0); STAGE(1); STAGE(2);
  asm volatile("s_waitcnt vmcnt(8)" ::: "memory");
  BARR;

#pragma unroll
  for (int kt = 0; kt < 16; ++kt) {
    if (kt < 13) STAGE(kt + 3);                  // prefetch distance 3
    const unsigned short* asb = &As[kt & 3][0];
    const unsigned short* bsb = &Bs[kt & 3][0];
    bf16x8_t af[8], bf[4];
#pragma unroll
    for (int ni = 0; ni < 4; ++ni)
      bf[ni] = *(const bf16x8_t*)&bsb[(wn * 64 + ni * 16 + fr) * 32 + ((g ^ kf) * 8)];
#pragma unroll
    for (int mi = 0; mi < 8; ++mi)
      af[mi] = *(const bf16x8_t*)&asb[(wm * 128 + mi * 16 + fr) * 32 + ((g ^ kf) * 8)];
    __builtin_amdgcn_s_setprio(1);
#pragma unroll
    for (int mi = 0; mi < 8; ++mi)
#pragma unroll
      for (int ni = 0; ni < 4; ++ni)
        acc[mi][ni] = __builtin_amdgcn_mfma_f32_16x16x32_bf16(af[mi], bf[ni], acc[mi][ni], 0, 0, 0);
    __builtin_amdgcn_s_setprio(0);
    if (kt < 15) {
      // counted wait: buffer kt+1 resident; tiles kt+2,kt+3 stay in flight
      if (kt <= 12)      asm volatile("s_waitcnt vmcnt(8)" ::: "memory");
      else if (kt == 13) asm volatile("s_waitcnt vmcnt(4)" ::: "memory");
      else               asm volatile("s_waitcnt vmcnt(0)" ::: "memory");
      BARR;
    }
  }
#undef STAGE

  // epilogue: C/D mapping col=lane&15, row=(lane>>4)*4+reg. Row-burst order.
  const int cr = (lane >> 4) * 4, cc = lane & 15;
  float bv[4], lsum[4], lsq[4];
#pragma unroll
  for (int ni = 0; ni < 4; ++ni) {
    bv[ni] = bias[n0 + wn * 64 + ni * 16 + cc];
    lsum[ni] = 0.f; lsq[ni] = 0.f;
  }
#pragma unroll
  for (int mi = 0; mi < 8; ++mi) {
#pragma unroll
    for (int jj = 0; jj < 4; ++jj) {
      const size_t row = (size_t)(m0 + wm * 128 + mi * 16 + cr + jj);
#pragma unroll
      for (int ni = 0; ni < 4; ++ni) {
        int col = n0 + wn * 64 + ni * 16 + cc;
        float v = acc[mi][ni][jj] + bv[ni];
        if (OUT_BF16) Cb[row * N + col] = f2bf(v);
        else          Cf[row * N + col] = v;
        if (STATS) { lsum[ni] += v; lsq[ni] += v * v; }
      }
    }
  }
  if (STATS) {
#pragma unroll
    for (int ni = 0; ni < 4; ++ni) {
      float s = lsum[ni], q = lsq[ni];
      s += __shfl_xor(s, 16); s += __shfl_xor(s, 32);
      q += __shfl_xor(q, 16); q += __shfl_xor(q, 32);
      if (lane < 16) {                 // cc == lane here
        int col = n0 + wn * 64 + ni * 16 + lane;
        atomicAdd(&gstats[col], s);
        atomicAdd(&gstats[512 + col], q);
      }
    }
  }
}

// ------------------------------------------ finalize column stats from atomic sums
__global__ __launch_bounds__(512) void statsfin_kernel(const float* __restrict__ part,
                                                       float* __restrict__ stats, int off) {
  int t = threadIdx.x;
  float mean = part[t] / 32768.f;
  float var = part[512 + t] / 32768.f - mean * mean;
  stats[off + t] = mean;
  stats[off + 512 + t] = rsqrtf(var + 1e-5f);
}

// ---------------------------------------------------------------- small attention
__global__ __launch_bounds__(256) void attn2_kernel(const unsigned short* __restrict__ qkv,
                                                    unsigned short* __restrict__ ctxb) {
  const int n = blockIdx.x, h = blockIdx.y, t = threadIdx.x;
  __shared__ float qs[32 * 68], ks[32 * 68], vs[32 * 68], ss[32 * 33];
  const int l = t >> 3, j0 = (t & 7) * 8;
  size_t rowb = ((size_t)(l * 1024 + n)) * 1536 + h * 64 + j0;
  us8_t qv = *(const us8_t*)(qkv + rowb);
  us8_t kv = *(const us8_t*)(qkv + rowb + 512);
  us8_t vv = *(const us8_t*)(qkv + rowb + 1024);
#pragma unroll
  for (int j = 0; j < 8; ++j) {
    qs[l * 68 + j0 + j] = b2f(qv[j]) * 0.125f;
    ks[l * 68 + j0 + j] = b2f(kv[j]);
    vs[l * 68 + j0 + j] = b2f(vv[j]);
  }
  __syncthreads();
  for (int o = t; o < 1024; o += 256) {
    int ll = o >> 5, m = o & 31;
    const float4* q4 = (const float4*)&qs[ll * 68];
    const float4* k4 = (const float4*)&ks[m * 68];
    float s = 0.f;
#pragma unroll
    for (int dd = 0; dd < 16; ++dd) {
      float4 a = q4[dd], b = k4[dd];
      s += a.x * b.x + a.y * b.y + a.z * b.z + a.w * b.w;
    }
    ss[ll * 33 + m] = s;
  }
  __syncthreads();
  if (t < 32) {
    float mx = -3e38f;
    for (int m = 0; m < 32; ++m) mx = fmaxf(mx, ss[t * 33 + m]);
    float sum = 0.f;
    for (int m = 0; m < 32; ++m) { float e = __expf(ss[t * 33 + m] - mx); ss[t * 33 + m] = e; sum += e; }
    float inv = 1.f / sum;
    for (int m = 0; m < 32; ++m) ss[t * 33 + m] *= inv;
  }
  __syncthreads();
  float o[8] = {0.f, 0.f, 0.f, 0.f, 0.f, 0.f, 0.f, 0.f};
#pragma unroll 8
  for (int m = 0; m < 32; ++m) {
    float pm = ss[l * 33 + m];
    const float* vr = &vs[m * 68 + j0];
#pragma unroll
    for (int j = 0; j < 8; ++j) o[j] += pm * vr[j];
  }
  us8_t ov;
#pragma unroll
  for (int j = 0; j < 8; ++j) ov[j] = f2bf(o[j]);
  *(us8_t*)(ctxb + ((size_t)(l * 1024 + n)) * 512 + h * 64 + j0) = ov;
}

// ---------------------------------------------------------------- projection (M x 8), fp32 x
__global__ __launch_bounds__(256) void proj_kernel(const float* __restrict__ x,
    const float* __restrict__ pw, const float* __restrict__ pb, float* __restrict__ p) {
  int blk = blockIdx.x, t = threadIdx.x;
  int r0 = blk * 64;
  __shared__ float xsp[64 * 33];
  __shared__ float pwc[8 * 33];
  int l = t >> 2, fg = t & 3;
  float acc0 = 0.f, acc1 = 0.f;
  for (int k0 = 0; k0 < 512; k0 += 32) {
    __syncthreads();
    for (int i = t; i < 2048; i += 256) { int ll = i >> 5, kk = i & 31; xsp[ll * 33 + kk] = x[(size_t)(r0 + ll) * 512 + k0 + kk]; }
    { int ff = t >> 5, kk = t & 31; pwc[ff * 33 + kk] = pw[ff * 512 + k0 + kk]; }
    __syncthreads();
#pragma unroll 8
    for (int kk = 0; kk < 32; ++kk) {
      float xv = xsp[l * 33 + kk];
      acc0 += xv * pwc[(fg * 2) * 33 + kk];
      acc1 += xv * pwc[(fg * 2 + 1) * 33 + kk];
    }
  }
  float2 o; o.x = acc0 + pb[fg * 2]; o.y = acc1 + pb[fg * 2 + 1];
  *(float2*)&p[(r0 + l) * 8 + fg * 2] = o;
}

// ---------------------------------------------------------------- proj BN stats (C=8)
__global__ __launch_bounds__(256) void projstats_kernel(const float* __restrict__ p,
                                                        float* __restrict__ part) {
  int t = threadIdx.x, blk = blockIdx.x;  // 64 blocks
  int f = t & 7;
  float s = 0.f, s2 = 0.f;
  for (int r = blk * 32 + (t >> 3); r < 32768; r += 2048) { float v = p[r * 8 + f]; s += v; s2 += v * v; }
  __shared__ float red[256], red2[256];
  red[t] = s; red2[t] = s2; __syncthreads();
  for (int off = 128; off >= 8; off >>= 1) { if (t < off) { red[t] += red[t + off]; red2[t] += red2[t + off]; } __syncthreads(); }
  if (t < 8) { part[blk * 16 + t] = red[t]; part[blk * 16 + 8 + t] = red2[t]; }
}
__global__ void projfin_kernel(const float* __restrict__ part, float* __restrict__ stats) {
  int t = threadIdx.x;
  if (t < 8) {
    float s = 0.f, s2 = 0.f;
    for (int b = 0; b < 64; ++b) { s += part[b * 16 + t]; s2 += part[b * 16 + 8 + t]; }
    float mean = s / 32768.f;
    float var = s2 / 32768.f - mean * mean;
    stats[SOFF_PMEAN + t] = mean;
    stats[SOFF_PRSTD + t] = rsqrtf(var + 1e-5f);
  }
}

// ------------------------------------------------- apply proj-BN in place + min/max
__global__ __launch_bounds__(256) void bnminmax_kernel(float* __restrict__ p,
    const float* __restrict__ stats, const float* __restrict__ png,
    const float* __restrict__ pnb, float* __restrict__ part) {
  int t = threadIdx.x, blk = blockIdx.x;  // 64 blocks
  int i0 = blk * 256 + t;
  int f = i0 & 7;
  float k1 = stats[SOFF_PRSTD + f] * png[f];
  float k0 = pnb[f] - stats[SOFF_PMEAN + f] * k1;
  float mn = 3e38f, mx = -3e38f;
  for (int i = i0; i < 262144; i += 16384) {
    float v = p[i] * k1 + k0;
    p[i] = v;
    mn = fminf(mn, v); mx = fmaxf(mx, v);
  }
  __shared__ float rmn[256], rmx[256];
  rmn[t] = mn; rmx[t] = mx; __syncthreads();
  for (int off = 128; off >= 8; off >>= 1) {
    if (t < off) { rmn[t] = fminf(rmn[t], rmn[t + off]); rmx[t] = fmaxf(rmx[t], rmx[t + off]); }
    __syncthreads();
  }
  if (t < 8) { part[blk * 16 + t] = rmn[t]; part[blk * 16 + 8 + t] = rmx[t]; }
}
__global__ void minmaxfin_kernel(const float* __restrict__ part, float* __restrict__ stats) {
  int t = threadIdx.x;
  if (t < 8) {
    float mn = 3e38f, mx = -3e38f;
    for (int b = 0; b < 64; ++b) { mn = fminf(mn, part[b * 16 + t]); mx = fmaxf(mx, part[b * 16 + 8 + t]); }
    stats[SOFF_FMIN + t] = mn;
    stats[SOFF_FMAX + t] = mx;
  }
}

// ---------------------------------------------------------------- spline (in place)
__global__ __launch_bounds__(256) void spline_kernel(float* __restrict__ p,
    const float* __restrict__ knots, const float* __restrict__ cps,
    const float* __restrict__ stats) {
  __shared__ float ksh[8 * 33], csh[8 * 33];
  int t = threadIdx.x;
  { int f = t >> 5, j = t & 31; ksh[f * 33 + j] = knots[t]; csh[f * 33 + j] = cps[t]; }
  __syncthreads();
  int i = blockIdx.x * 256 + t;
  int f = i & 7;
  float xv = p[i];
  float mn = stats[SOFF_FMIN + f], mx = stats[SOFF_FMAX + f];
  float xn = (xv - mn) / (mx - mn + 1e-6f);
  const float* kn = &ksh[f * 33];
  const float* cp = &csh[f * 33];
  int pcnt = 0;
#pragma unroll
  for (int j = 0; j < 32; ++j) pcnt += (kn[j] <= xn) ? 1 : 0;
  int idx = pcnt - 1;
  idx = idx < 0 ? 0 : (idx > 30 ? 30 : idx);
  float k0v = kn[idx], k1v = kn[idx + 1];
  float tt = (xn - k0v) / (k1v - k0v);
  float val = (1.f - tt) * cp[idx] + tt * cp[idx + 1];
  bool inr = (xn >= kn[0]) && (xn <= kn[31]);
  p[i] = inr ? val : 0.f;
}

// ------------------------------------------- gate-weight Grams (parallel, 88 blocks)
__global__ __launch_bounds__(256) void gateprep_kernel(const float* __restrict__ gw,
    const float* __restrict__ gb, float* __restrict__ stats) {
  int b = blockIdx.x, t = threadIdx.x;
  __shared__ float red[256];
  float s = 0.f;
  if (b < 64) {
    int f1 = b >> 3, f2 = b & 7;
    for (int j = t; j < 1024; j += 256) s += gw[j * 8 + f1] * gw[j * 8 + f2];
  } else if (b < 72) {
    int f = b - 64;
    for (int j = t; j < 1024; j += 256) s += gw[j * 8 + f];
  } else if (b < 80) {
    int f = b - 72;
    for (int j = t; j < 1024; j += 256) s += gb[j] * gw[j * 8 + f];
  } else if (b == 80) {
    for (int j = t; j < 1024; j += 256) s += gb[j];
  } else {
    for (int j = t; j < 1024; j += 256) s += gb[j] * gb[j];
  }
  red[t] = s; __syncthreads();
  for (int off = 128; off > 0; off >>= 1) { if (t < off) red[t] += red[t + off]; __syncthreads(); }
  if (t == 0) {
    float v = red[0];
    if (b < 64) stats[SOFF_G2 + b] = v;
    else if (b < 72) stats[SOFF_G1 + (b - 64)] = v;
    else if (b < 80) stats[SOFF_GB + (b - 72)] = v;
    else if (b == 80) stats[SOFF_SGB] = v;
    else stats[SOFF_QGB] = v;
  }
}

// -------------------------------------- per-s BN stats of h WITHOUT materializing h
__global__ __launch_bounds__(256) void sstats_kernel(const float* __restrict__ tbuf,
                                                     float* __restrict__ stats) {
  int s = blockIdx.x, t = threadIdx.x;
  __shared__ float tv[256];
  __shared__ float red[256];
  __shared__ float T1[8];
  __shared__ float Ms[64];
  int b = t >> 3, f = t & 7;
  tv[t] = tbuf[(b * 1024 + s) * 8 + f];
  __syncthreads();
  red[t] = tv[t]; __syncthreads();
  for (int off = 128; off >= 8; off >>= 1) { if (t < off) red[t] += red[t + off]; __syncthreads(); }
  if (t < 8) T1[t] = red[t];
  if (t < 64) {
    int f1 = t >> 3, f2 = t & 7; float sM = 0.f;
    for (int bb = 0; bb < 32; ++bb) sM += tv[bb * 8 + f1] * tv[bb * 8 + f2];
    Ms[t] = sM;
  }
  __syncthreads();
  if (t == 0) {
    float sh = 0.f, s2 = 0.f;
    for (int ff = 0; ff < 8; ++ff) {
      sh += stats[SOFF_G1 + ff] * T1[ff];
      s2 += 2.f * stats[SOFF_GB + ff] * T1[ff];
    }
    sh += 32.f * stats[SOFF_SGB];
    for (int i = 0; i < 64; ++i) s2 += Ms[i] * stats[SOFF_G2 + i];
    s2 += 32.f * stats[SOFF_QGB];
    float mean = sh / 32768.f;
    float var = s2 / 32768.f - mean * mean;
    stats[SOFF_SMEAN + s] = mean;
    stats[SOFF_SRSTD + s] = rsqrtf(var + 1e-5f);
  }
}

// ---- recompute h row (fp32 gate_w — MUST match sstats' weights), BN-s, GLU, LN
__global__ __launch_bounds__(256) void gluln_kernel(const float* __restrict__ tbuf,
    const float* __restrict__ gw, const float* __restrict__ gb,
    const float* __restrict__ stats, const float* __restrict__ gbng,
    const float* __restrict__ gbnb, const float* __restrict__ lng,
    const float* __restrict__ lnb, unsigned short* __restrict__ gatedb) {
  const int t = threadIdx.x, wave = t >> 6, lane = t & 63;
  for (int rr = 0; rr < 4; ++rr) {
    const int r = blockIdx.x * 16 + wave * 4 + rr;
    const int s = r & 1023;
    float4 tA = *(const float4*)&tbuf[r * 8];
    float4 tB = *(const float4*)&tbuf[r * 8 + 4];
    float smean = stats[SOFF_SMEAN + s], srstd = stats[SOFF_SRSTD + s];
    float k1 = srstd * gbng[s];
    float k0 = gbnb[s] - smean * k1;
    float g[8];
    float sum = 0.f, sq = 0.f;
#pragma unroll
    for (int i = 0; i < 8; ++i) {
      int c = i * 64 + lane;
      float4 wa0 = *(const float4*)&gw[c * 8];
      float4 wa1 = *(const float4*)&gw[c * 8 + 4];
      float4 wb0 = *(const float4*)&gw[(c + 512) * 8];
      float4 wb1 = *(const float4*)&gw[(c + 512) * 8 + 4];
      float ha = tA.x * wa0.x + tA.y * wa0.y + tA.z * wa0.z + tA.w * wa0.w
               + tB.x * wa1.x + tB.y * wa1.y + tB.z * wa1.z + tB.w * wa1.w + gb[c];
      float hb = tA.x * wb0.x + tA.y * wb0.y + tA.z * wb0.z + tA.w * wb0.w
               + tB.x * wb1.x + tB.y * wb1.y + tB.z * wb1.z + tB.w * wb1.w + gb[c + 512];
      ha = ha * k1 + k0;
      hb = hb * k1 + k0;
      float gv = ha / (1.f + __expf(-hb));
      g[i] = gv; sum += gv; sq += gv * gv;
    }
#pragma unroll
    for (int m = 32; m >= 1; m >>= 1) { sum += __shfl_xor(sum, m); sq += __shfl_xor(sq, m); }
    float mean = sum * (1.f / 512.f);
    float rstd = rsqrtf(sq * (1.f / 512.f) - mean * mean + 1e-5f);
#pragma unroll
    for (int i = 0; i < 8; ++i) {
      int c = i * 64 + lane;
      gatedb[(size_t)r * 512 + c] = f2bf((g[i] - mean) * rstd * lng[c] + lnb[c]);
    }
  }
}

// ---------------------------------------------------------------- final elementwise
__global__ __launch_bounds__(256) void final_kernel(const float* __restrict__ x,
    const float* __restrict__ attn, const float* __restrict__ outl,
    const float* __restrict__ stats, const float* __restrict__ ag,
    const float* __restrict__ ab, const float* __restrict__ og,
    const float* __restrict__ ob, float* __restrict__ y) {
  int idx = blockIdx.x * 256 + threadIdx.x;
  int c4 = (idx & 127) * 4;
  float4 xv = ((const float4*)x)[idx];
  float4 av = ((const float4*)attn)[idx];
  float4 ov = ((const float4*)outl)[idx];
  float4 am = *(const float4*)&stats[SOFF_AMEAN + c4];
  float4 ar = *(const float4*)&stats[SOFF_ARSTD + c4];
  float4 om = *(const float4*)&stats[SOFF_OMEAN + c4];
  float4 orr = *(const float4*)&stats[SOFF_ORSTD + c4];
  float4 g1 = *(const float4*)&ag[c4];
  float4 b1 = *(const float4*)&ab[c4];
  float4 g2 = *(const float4*)&og[c4];
  float4 b2 = *(const float4*)&ob[c4];
  float4 o;
  o.x = xv.x + (av.x - am.x) * ar.x * g1.x + b1.x + (ov.x - om.x) * orr.x * g2.x + b2.x;
  o.y = xv.y + (av.y - am.y) * ar.y * g1.y + b1.y + (ov.y - om.y) * orr.y * g2.y + b2.y;
  o.z = xv.z + (av.z - am.z) * ar.z * g1.z + b1.z + (ov.z - om.z) * orr.z * g2.z + b2.z;
  o.w = xv.w + (av.w - am.w) * ar.w * g1.w + b1.w + (ov.w - om.w) * orr.w * g2.w + b2.w;
  ((float4*)y)[idx] = o;
}

extern "C" void kernel_launch(void* const* d_in, const int* in_sizes, int n_in,
                              void* d_out, int out_size, void* d_ws, size_t ws_size,
                              hipStream_t stream) {
  (void)in_sizes; (void)n_in; (void)out_size; (void)ws_size;
  const float* x        = (const float*)d_in[0];
  const float* in_w     = (const float*)d_in[1];
  const float* in_b     = (const float*)d_in[2];
  const float* out_w    = (const float*)d_in[3];
  const float* out_b    = (const float*)d_in[4];
  const float* attn_g   = (const float*)d_in[5];
  const float* attn_bt  = (const float*)d_in[6];
  const float* proj_w   = (const float*)d_in[7];
  const float* proj_b   = (const float*)d_in[8];
  const float* pn_g     = (const float*)d_in[9];
  const float* pn_bt    = (const float*)d_in[10];
  const float* knots    = (const float*)d_in[11];
  const float* cps      = (const float*)d_in[12];
  const float* gate_w   = (const float*)d_in[13];
  const float* gate_b   = (const float*)d_in[14];
  const float* gbn_g    = (const float*)d_in[15];
  const float* gbn_bt   = (const float*)d_in[16];
  const float* ln_g     = (const float*)d_in[17];
  const float* ln_bt    = (const float*)d_in[18];
  const float* outp_w   = (const float*)d_in[19];
  const float* outp_b   = (const float*)d_in[20];
  const float* on_g     = (const float*)d_in[21];
  const float* on_bt    = (const float*)d_in[22];

  float* out = (float*)d_out;
  unsigned short* xb      = (unsigned short*)d_ws;      // 16777216
  unsigned short* qkv_b   = xb + 16777216;              // 50331648
  unsigned short* ctx_b   = qkv_b + 50331648;           // 16777216
  unsigned short* wqkv_b  = ctx_b + 16777216;           // 786432
  unsigned short* wout_b  = wqkv_b + 786432;            // 262144
  unsigned short* woutp_b = wout_b + 262144;            // 262144
  float* proj  = (float*)(woutp_b + 262144);            // 262144 floats
  float* stats = proj + 262144;
  float* part  = stats + SOFF_PART;                     // 4096 floats
  float* partA  = part;                                 // 1024 (atomic col stats attn)
  float* partO  = part + 1024;                          // 1024 (atomic col stats out)
  float* partP  = part + 2048;                          // 1024 (projstats partials)
  float* partMM = part + 3072;                          // 1024 (minmax partials)
  float* attnf = (float*)qkv_b;      // alias: qkv dead after attn2
  unsigned short* gated_b = xb;      // alias: xb dead after qkv GEMM

  zero_kernel<<<dim3(8), dim3(256), 0, stream>>>(part);   // partA+partO
  cvt8_kernel<<<dim3(8192), dim3(256), 0, stream>>>(x, xb);
  cvt8_kernel<<<dim3(384), dim3(256), 0, stream>>>(in_w, wqkv_b);
  cvt8_kernel<<<dim3(128), dim3(256), 0, stream>>>(out_w, wout_b);
  cvt8_kernel<<<dim3(128), dim3(256), 0, stream>>>(outp_w, woutp_b);
  // qkv = x @ in_w^T + in_b -> bf16   (128 m-tiles x 6 n-tiles = 768 blocks)
  gemm256_kernel<6, true, false><<<dim3(768), dim3(512), 0, stream>>>(
      xb, wqkv_b, in_b, qkv_b, nullptr, nullptr, 1536);
  attn2_kernel<<<dim3(1024, 8), dim3(256), 0, stream>>>(qkv_b, ctx_b);
  // attn_lin = ctx @ out_w^T + out_b -> fp32 (+ fused column stats)
  gemm256_kernel<2, false, true><<<dim3(256), dim3(512), 0, stream>>>(
      ctx_b, wout_b, out_b, nullptr, attnf, partA, 512);
  statsfin_kernel<<<dim3(1), dim3(512), 0, stream>>>(partA, stats, SOFF_AMEAN);
  proj_kernel<<<dim3(512), dim3(256), 0, stream>>>(x, proj_w, proj_b, proj);
  projstats_kernel<<<dim3(64), dim3(256), 0, stream>>>(proj, partP);
  projfin_kernel<<<dim3(1), dim3(64), 0, stream>>>(partP, stats);
  bnminmax_kernel<<<dim3(64), dim3(256), 0, stream>>>(proj, stats, pn_g, pn_bt, partMM);
  minmaxfin_kernel<<<dim3(1), dim3(64), 0, stream>>>(partMM, stats);
  spline_kernel<<<dim3(1024), dim3(256), 0, stream>>>(proj, knots, cps, stats);
  gateprep_kernel<<<dim3(88), dim3(256), 0, stream>>>(gate_w, gate_b, stats);
  sstats_kernel<<<dim3(1024), dim3(256), 0, stream>>>(proj, stats);
  gluln_kernel<<<dim3(2048), dim3(256), 0, stream>>>(proj, gate_w, gate_b, stats,
                                                     gbn_g, gbn_bt, ln_g, ln_bt, gated_b);
  // out = gated @ outp_w^T + outp_b -> fp32 (+ fused column stats)
  gemm256_kernel<2, false, true><<<dim3(256), dim3(512), 0, stream>>>(
      gated_b, woutp_b, outp_b, nullptr, out, partO, 512);
  statsfin_kernel<<<dim3(1), dim3(512), 0, stream>>>(partO, stats, SOFF_OMEAN);
  final_kernel<<<dim3(16384), dim3(256), 0, stream>>>(x, attnf, out, stats,
                                                      attn_g, attn_bt, on_g, on_bt, out);
}

// Round 4
// 470.289 us; speedup vs baseline: 1.1355x; 1.1110x over previous
//
#include <hip/hip_runtime.h>
#include <math.h>

// B=32, S=1024, D=512, F=8, KN=32 knots, H=8, hd=64. M = B*S = 32768 rows.

#define SOFF_AMEAN 0
#define SOFF_ARSTD 512
#define SOFF_OMEAN 1024
#define SOFF_ORSTD 1536
#define SOFF_PMEAN 2048
#define SOFF_PRSTD 2056
#define SOFF_FMIN  2064
#define SOFF_FMAX  2072
#define SOFF_SMEAN 2080
#define SOFF_SRSTD 3104
#define SOFF_G1    4128
#define SOFF_GB    4136
#define SOFF_SGB   4144
#define SOFF_QGB   4145
#define SOFF_G2    4160
#define SOFF_PART  4224

typedef short bf16x8_t __attribute__((ext_vector_type(8)));
typedef float f32x4_t __attribute__((ext_vector_type(4)));
typedef unsigned short us8_t __attribute__((ext_vector_type(8)));

__device__ __forceinline__ unsigned short f2bf(float f) {
  unsigned u = __float_as_uint(f);
  u = (u + 0x7FFFu + ((u >> 16) & 1u)) >> 16;
  return (unsigned short)u;
}
__device__ __forceinline__ float b2f(unsigned short u) {
  return __uint_as_float(((unsigned)u) << 16);
}

// compile-time-only reordering fence around raw s_barrier (NO waitcnt drain)
#define BARR do { asm volatile("" ::: "memory"); __builtin_amdgcn_s_barrier(); asm volatile("" ::: "memory"); } while (0)

// ---------------------------------------------------------------- zero scratch
__global__ __launch_bounds__(256) void zero_kernel(float* __restrict__ p) {
  p[blockIdx.x * 256 + threadIdx.x] = 0.f;
}

// ---------------------------------------------------------------- fp32 -> bf16
__global__ __launch_bounds__(256) void cvt8_kernel(const float* __restrict__ src,
                                                   unsigned short* __restrict__ dst) {
  int i = blockIdx.x * 256 + threadIdx.x;
  float4 a = ((const float4*)src)[i * 2];
  float4 b = ((const float4*)src)[i * 2 + 1];
  us8_t o;
  o[0] = f2bf(a.x); o[1] = f2bf(a.y); o[2] = f2bf(a.z); o[3] = f2bf(a.w);
  o[4] = f2bf(b.x); o[5] = f2bf(b.y); o[6] = f2bf(b.z); o[7] = f2bf(b.w);
  *(us8_t*)(dst + (size_t)i * 8) = o;
}

// ------------------------------------------------- bf16 MFMA GEMM  C = A@B^T + bias
// 256x256 tile, BK=32, 8 waves (2Mx4N). Quad-buffered ring, prefetch distance 3,
// counted vmcnt(8) at tile boundaries. (R2: verified, QKV GEMM < 75 us.)
template<int NT, bool OUT_BF16, bool STATS>
__global__ __launch_bounds__(512, 2) void gemm256_kernel(
    const unsigned short* __restrict__ A, const unsigned short* __restrict__ B,
    const float* __restrict__ bias, unsigned short* __restrict__ Cb,
    float* __restrict__ Cf, float* __restrict__ gstats, int N) {
  __shared__ unsigned short As[4][256 * 32];
  __shared__ unsigned short Bs[4][256 * 32];
  const int bi = blockIdx.x;
  const int xcd = bi & 7, jb = bi >> 3;          // 128 M-tiles: 16 per XCD
  const int m0 = (xcd * 16 + jb / NT) * 256;
  const int n0 = (jb % NT) * 256;
  const int t = threadIdx.x;
  const int w = t >> 6, lane = t & 63;
  const int wm = w >> 2, wn = w & 3;             // 2 x 4 wave grid

  const unsigned short* gA = A + (size_t)(m0 + w * 16 + (lane >> 2)) * 512
                               + (((lane & 3) ^ ((lane >> 3) & 3)) * 8);
  const unsigned short* gB = B + (size_t)(n0 + w * 16 + (lane >> 2)) * 512
                               + (((lane & 3) ^ ((lane >> 3) & 3)) * 8);

  const int fr = lane & 15, g = lane >> 4;
  const int kf = (fr >> 1) & 3;

  f32x4_t acc[8][4];
#pragma unroll
  for (int i = 0; i < 8; ++i)
#pragma unroll
    for (int jj = 0; jj < 4; ++jj) acc[i][jj] = (f32x4_t){0.f, 0.f, 0.f, 0.f};

#define STAGE(KT) do { \
    __builtin_amdgcn_global_load_lds( \
        (const __attribute__((address_space(1))) void*)(gA + (KT) * 32), \
        (__attribute__((address_space(3))) void*)&As[(KT) & 3][(w * 16) * 32], 16, 0, 0); \
    __builtin_amdgcn_global_load_lds( \
        (const __attribute__((address_space(1))) void*)(gA + (KT) * 32 + 128 * 512), \
        (__attribute__((address_space(3))) void*)&As[(KT) & 3][(128 + w * 16) * 32], 16, 0, 0); \
    __builtin_amdgcn_global_load_lds( \
        (const __attribute__((address_space(1))) void*)(gB + (KT) * 32), \
        (__attribute__((address_space(3))) void*)&Bs[(KT) & 3][(w * 16) * 32], 16, 0, 0); \
    __builtin_amdgcn_global_load_lds( \
        (const __attribute__((address_space(1))) void*)(gB + (KT) * 32 + 128 * 512), \
        (__attribute__((address_space(3))) void*)&Bs[(KT) & 3][(128 + w * 16) * 32], 16, 0, 0); \
  } while (0)

  STAGE(0); STAGE(1); STAGE(2);
  asm volatile("s_waitcnt vmcnt(8)" ::: "memory");
  BARR;

#pragma unroll
  for (int kt = 0; kt < 16; ++kt) {
    if (kt < 13) STAGE(kt + 3);                  // prefetch distance 3
    const unsigned short* asb = &As[kt & 3][0];
    const unsigned short* bsb = &Bs[kt & 3][0];
    bf16x8_t af[8], bf[4];
#pragma unroll
    for (int ni = 0; ni < 4; ++ni)
      bf[ni] = *(const bf16x8_t*)&bsb[(wn * 64 + ni * 16 + fr) * 32 + ((g ^ kf) * 8)];
#pragma unroll
    for (int mi = 0; mi < 8; ++mi)
      af[mi] = *(const bf16x8_t*)&asb[(wm * 128 + mi * 16 + fr) * 32 + ((g ^ kf) * 8)];
    __builtin_amdgcn_s_setprio(1);
#pragma unroll
    for (int mi = 0; mi < 8; ++mi)
#pragma unroll
      for (int ni = 0; ni < 4; ++ni)
        acc[mi][ni] = __builtin_amdgcn_mfma_f32_16x16x32_bf16(af[mi], bf[ni], acc[mi][ni], 0, 0, 0);
    __builtin_amdgcn_s_setprio(0);
    if (kt < 15) {
      if (kt <= 12)      asm volatile("s_waitcnt vmcnt(8)" ::: "memory");
      else if (kt == 13) asm volatile("s_waitcnt vmcnt(4)" ::: "memory");
      else               asm volatile("s_waitcnt vmcnt(0)" ::: "memory");
      BARR;
    }
  }
#undef STAGE

  // epilogue: C/D mapping col=lane&15, row=(lane>>4)*4+reg. Row-burst order.
  const int cr = (lane >> 4) * 4, cc = lane & 15;
  float bv[4], lsum[4], lsq[4];
#pragma unroll
  for (int ni = 0; ni < 4; ++ni) {
    bv[ni] = bias[n0 + wn * 64 + ni * 16 + cc];
    lsum[ni] = 0.f; lsq[ni] = 0.f;
  }
#pragma unroll
  for (int mi = 0; mi < 8; ++mi) {
#pragma unroll
    for (int jj = 0; jj < 4; ++jj) {
      const size_t row = (size_t)(m0 + wm * 128 + mi * 16 + cr + jj);
#pragma unroll
      for (int ni = 0; ni < 4; ++ni) {
        int col = n0 + wn * 64 + ni * 16 + cc;
        float v = acc[mi][ni][jj] + bv[ni];
        if (OUT_BF16) Cb[row * N + col] = f2bf(v);
        else          Cf[row * N + col] = v;
        if (STATS) { lsum[ni] += v; lsq[ni] += v * v; }
      }
    }
  }
  if (STATS) {
#pragma unroll
    for (int ni = 0; ni < 4; ++ni) {
      float s = lsum[ni], q = lsq[ni];
      s += __shfl_xor(s, 16); s += __shfl_xor(s, 32);
      q += __shfl_xor(q, 16); q += __shfl_xor(q, 32);
      if (lane < 16) {
        int col = n0 + wn * 64 + ni * 16 + lane;
        atomicAdd(&gstats[col], s);
        atomicAdd(&gstats[512 + col], q);
      }
    }
  }
}

// ------------------------------------------ finalize column stats from atomic sums
__global__ __launch_bounds__(512) void statsfin_kernel(const float* __restrict__ part,
                                                       float* __restrict__ stats, int off) {
  int t = threadIdx.x;
  float mean = part[t] / 32768.f;
  float var = part[512 + t] / 32768.f - mean * mean;
  stats[off + t] = mean;
  stats[off + 512 + t] = rsqrtf(var + 1e-5f);
}

// ---------------------------------------------------------------- MFMA attention
// One wave per (n,h). L=32 keys/queries, d=64. All fragment layouts are the
// 16x16x32 mappings verified by gemm256 (A/B row=lane&15, k=(lane>>4)*8+j;
// C/D col=lane&15, row=(lane>>4)*4+reg). mfma(Xf,Yf) = X·Y^T.
//   st = K·Q^T (scores^T): lane holds S[l = li*16+fr][m = mi*16+g*4+r].
//   softmax over m: 8 local + shfl_xor(16)+shfl_xor(32).
//   P->bf16 A-frag: pack pairs, 2 shfl rounds (xor16, xor32) + selects.
//   PV: out = P·(V^T)^T via B-frag from vt[d][m] (V transposed into LDS during
//   staging with a lane-pair pack; write banks within quarter-wave distinct).
__global__ __launch_bounds__(64) void attn3_kernel(const unsigned short* __restrict__ qkv,
                                                   unsigned short* __restrict__ ctxb) {
  const int n = blockIdx.x, h = blockIdx.y;
  const int lane = threadIdx.x;
  const int fr = lane & 15, g = lane >> 4;
  const int r = lane & 31, hi2 = lane >> 5;
  __shared__ unsigned short vt[64 * 32];   // vt[d][m] = V[m][d]

  const unsigned short* base = qkv + (size_t)n * 1536 + (size_t)h * 64;

  // ---- V load (rows r, 16B chunks) + in-register pair-transpose -> vt
#pragma unroll
  for (int i = 0; i < 4; ++i) {
    const int d0 = (i * 2 + hi2) * 8;
    union { us8_t v; unsigned u[4]; } ov;
    ov.v = *(const us8_t*)(base + (size_t)r * 1572864 + 1024 + d0);
#pragma unroll
    for (int w = 0; w < 4; ++w) {
      unsigned o = ov.u[w];
      unsigned pu = __shfl_xor(o, 1);
      // even r writes d0+2w   : (V[r][d] , V[r+1][d])   = (o lo, p lo)
      // odd  r writes d0+2w+1 : (V[r-1][d], V[r][d])    = (p hi, o hi)
      unsigned val = (r & 1) ? ((pu >> 16) | (o & 0xFFFF0000u))
                             : ((o & 0xFFFFu) | (pu << 16));
      int dw = d0 + 2 * w + (r & 1);
      *(unsigned*)&vt[dw * 32 + (r >> 1) * 2] = val;
    }
  }

  // ---- K/Q fragments direct from global (bf16, no staging)
  bf16x8_t kfr[2][2], qfr[2][2];
#pragma unroll
  for (int mi = 0; mi < 2; ++mi)
#pragma unroll
    for (int s = 0; s < 2; ++s)
      kfr[mi][s] = *(const bf16x8_t*)(base + (size_t)(mi * 16 + fr) * 1572864 + 512 + s * 32 + g * 8);
#pragma unroll
  for (int li = 0; li < 2; ++li)
#pragma unroll
    for (int s = 0; s < 2; ++s)
      qfr[li][s] = *(const bf16x8_t*)(base + (size_t)(li * 16 + fr) * 1572864 + s * 32 + g * 8);

  // ---- scores^T = K·Q^T  (2x2 tiles, contraction d=64 => 2 mfma each)
  f32x4_t st[2][2];
#pragma unroll
  for (int mi = 0; mi < 2; ++mi)
#pragma unroll
    for (int li = 0; li < 2; ++li) {
      st[mi][li] = (f32x4_t){0.f, 0.f, 0.f, 0.f};
#pragma unroll
      for (int s = 0; s < 2; ++s)
        st[mi][li] = __builtin_amdgcn_mfma_f32_16x16x32_bf16(kfr[mi][s], qfr[li][s], st[mi][li], 0, 0, 0);
    }

  __syncthreads();   // vt ready
  bf16x8_t vf[4];
#pragma unroll
  for (int dj = 0; dj < 4; ++dj)
    vf[dj] = *(const bf16x8_t*)&vt[(dj * 16 + fr) * 32 + g * 8];

  const bool pj = (g & 1) != 0, hb = (g >> 1) != 0;
  f32x4_t outacc[2][4];
#pragma unroll
  for (int li = 0; li < 2; ++li) {
    // softmax over m for row l = li*16+fr (scale 1/8 folded into exp arg)
    float mx = -3e38f;
#pragma unroll
    for (int mi = 0; mi < 2; ++mi)
#pragma unroll
      for (int rr = 0; rr < 4; ++rr) mx = fmaxf(mx, st[mi][li][rr]);
    mx = fmaxf(mx, __shfl_xor(mx, 16));
    mx = fmaxf(mx, __shfl_xor(mx, 32));
    float e[2][4]; float sm = 0.f;
#pragma unroll
    for (int mi = 0; mi < 2; ++mi)
#pragma unroll
      for (int rr = 0; rr < 4; ++rr) {
        float ev = __expf((st[mi][li][rr] - mx) * 0.125f);
        e[mi][rr] = ev; sm += ev;
      }
    sm += __shfl_xor(sm, 16);
    sm += __shfl_xor(sm, 32);
    float inv = 1.f / sm;
    // pack normalized P: ww[mi][h] covers m = mi*16 + g*4 + 2h + {0,1}
    unsigned ww00 = ((unsigned)f2bf(e[0][1] * inv) << 16) | f2bf(e[0][0] * inv);
    unsigned ww01 = ((unsigned)f2bf(e[0][3] * inv) << 16) | f2bf(e[0][2] * inv);
    unsigned ww10 = ((unsigned)f2bf(e[1][1] * inv) << 16) | f2bf(e[1][0] * inv);
    unsigned ww11 = ((unsigned)f2bf(e[1][3] * inv) << 16) | f2bf(e[1][2] * inv);
    // round A: pair exchange (g ^ 1)
    unsigned pw00 = __shfl_xor(ww00, 16), pw01 = __shfl_xor(ww01, 16);
    unsigned pw10 = __shfl_xor(ww10, 16), pw11 = __shfl_xor(ww11, 16);
    // word(p,mi,h) = (p==pj) ? ww[mi][h] : pw[mi][h]
    // round B sends word(p, mi=!hb, h) across g^2 (lane^32)
    unsigned s00 = pj ? (hb ? pw00 : pw10) : (hb ? ww00 : ww10);
    unsigned s01 = pj ? (hb ? pw01 : pw11) : (hb ? ww01 : ww11);
    unsigned s10 = pj ? (hb ? ww00 : ww10) : (hb ? pw00 : pw10);
    unsigned s11 = pj ? (hb ? ww01 : ww11) : (hb ? pw01 : pw11);
    unsigned sb00 = __shfl_xor(s00, 32), sb01 = __shfl_xor(s01, 32);
    unsigned sb10 = __shfl_xor(s10, 32), sb11 = __shfl_xor(s11, 32);
    // keep words: word(p, mi=hb, h)
    unsigned k00 = pj ? (hb ? pw10 : pw00) : (hb ? ww10 : ww00);
    unsigned k01 = pj ? (hb ? pw11 : pw01) : (hb ? ww11 : ww01);
    unsigned k10 = pj ? (hb ? ww10 : ww00) : (hb ? pw10 : pw00);
    unsigned k11 = pj ? (hb ? ww11 : ww01) : (hb ? pw11 : pw01);
    const bool take = (pj != hb);
    union { unsigned u[4]; bf16x8_t v; } pa;
    pa.u[0] = take ? sb00 : k00;
    pa.u[1] = take ? sb01 : k01;
    pa.u[2] = take ? sb10 : k10;
    pa.u[3] = take ? sb11 : k11;
    // PV: out_tile(li,dj) = P·V  (single mfma, K=32)
#pragma unroll
    for (int dj = 0; dj < 4; ++dj)
      outacc[li][dj] = __builtin_amdgcn_mfma_f32_16x16x32_bf16(
          pa.v, vf[dj], (f32x4_t){0.f, 0.f, 0.f, 0.f}, 0, 0, 0);
  }

  // ---- store ctx (bf16): out[l][d], l = li*16+g*4+rr, d = dj*16+fr
#pragma unroll
  for (int li = 0; li < 2; ++li)
#pragma unroll
    for (int dj = 0; dj < 4; ++dj)
#pragma unroll
      for (int rr = 0; rr < 4; ++rr) {
        int l = li * 16 + g * 4 + rr;
        ctxb[((size_t)l * 1024 + n) * 512 + h * 64 + dj * 16 + fr] = f2bf(outacc[li][dj][rr]);
      }
}

// ---------------------------------------------------------------- projection (M x 8), fp32 x
__global__ __launch_bounds__(256) void proj_kernel(const float* __restrict__ x,
    const float* __restrict__ pw, const float* __restrict__ pb, float* __restrict__ p) {
  int blk = blockIdx.x, t = threadIdx.x;
  int r0 = blk * 64;
  __shared__ float xsp[64 * 33];
  __shared__ float pwc[8 * 33];
  int l = t >> 2, fg = t & 3;
  float acc0 = 0.f, acc1 = 0.f;
  for (int k0 = 0; k0 < 512; k0 += 32) {
    __syncthreads();
    for (int i = t; i < 2048; i += 256) { int ll = i >> 5, kk = i & 31; xsp[ll * 33 + kk] = x[(size_t)(r0 + ll) * 512 + k0 + kk]; }
    { int ff = t >> 5, kk = t & 31; pwc[ff * 33 + kk] = pw[ff * 512 + k0 + kk]; }
    __syncthreads();
#pragma unroll 8
    for (int kk = 0; kk < 32; ++kk) {
      float xv = xsp[l * 33 + kk];
      acc0 += xv * pwc[(fg * 2) * 33 + kk];
      acc1 += xv * pwc[(fg * 2 + 1) * 33 + kk];
    }
  }
  float2 o; o.x = acc0 + pb[fg * 2]; o.y = acc1 + pb[fg * 2 + 1];
  *(float2*)&p[(r0 + l) * 8 + fg * 2] = o;
}

// ---------------------------------------------------------------- proj BN stats (C=8)
__global__ __launch_bounds__(256) void projstats_kernel(const float* __restrict__ p,
                                                        float* __restrict__ part) {
  int t = threadIdx.x, blk = blockIdx.x;  // 64 blocks
  int f = t & 7;
  float s = 0.f, s2 = 0.f;
  for (int r = blk * 32 + (t >> 3); r < 32768; r += 2048) { float v = p[r * 8 + f]; s += v; s2 += v * v; }
  __shared__ float red[256], red2[256];
  red[t] = s; red2[t] = s2; __syncthreads();
  for (int off = 128; off >= 8; off >>= 1) { if (t < off) { red[t] += red[t + off]; red2[t] += red2[t + off]; } __syncthreads(); }
  if (t < 8) { part[blk * 16 + t] = red[t]; part[blk * 16 + 8 + t] = red2[t]; }
}
__global__ void projfin_kernel(const float* __restrict__ part, float* __restrict__ stats) {
  int t = threadIdx.x;
  if (t < 8) {
    float s = 0.f, s2 = 0.f;
    for (int b = 0; b < 64; ++b) { s += part[b * 16 + t]; s2 += part[b * 16 + 8 + t]; }
    float mean = s / 32768.f;
    float var = s2 / 32768.f - mean * mean;
    stats[SOFF_PMEAN + t] = mean;
    stats[SOFF_PRSTD + t] = rsqrtf(var + 1e-5f);
  }
}

// ------------------------------------------------- apply proj-BN in place + min/max
__global__ __launch_bounds__(256) void bnminmax_kernel(float* __restrict__ p,
    const float* __restrict__ stats, const float* __restrict__ png,
    const float* __restrict__ pnb, float* __restrict__ part) {
  int t = threadIdx.x, blk = blockIdx.x;  // 64 blocks
  int i0 = blk * 256 + t;
  int f = i0 & 7;
  float k1 = stats[SOFF_PRSTD + f] * png[f];
  float k0 = pnb[f] - stats[SOFF_PMEAN + f] * k1;
  float mn = 3e38f, mx = -3e38f;
  for (int i = i0; i < 262144; i += 16384) {
    float v = p[i] * k1 + k0;
    p[i] = v;
    mn = fminf(mn, v); mx = fmaxf(mx, v);
  }
  __shared__ float rmn[256], rmx[256];
  rmn[t] = mn; rmx[t] = mx; __syncthreads();
  for (int off = 128; off >= 8; off >>= 1) {
    if (t < off) { rmn[t] = fminf(rmn[t], rmn[t + off]); rmx[t] = fmaxf(rmx[t], rmx[t + off]); }
    __syncthreads();
  }
  if (t < 8) { part[blk * 16 + t] = rmn[t]; part[blk * 16 + 8 + t] = rmx[t]; }
}
__global__ void minmaxfin_kernel(const float* __restrict__ part, float* __restrict__ stats) {
  int t = threadIdx.x;
  if (t < 8) {
    float mn = 3e38f, mx = -3e38f;
    for (int b = 0; b < 64; ++b) { mn = fminf(mn, part[b * 16 + t]); mx = fmaxf(mx, part[b * 16 + 8 + t]); }
    stats[SOFF_FMIN + t] = mn;
    stats[SOFF_FMAX + t] = mx;
  }
}

// ---------------------------------------------------------------- spline (in place)
__global__ __launch_bounds__(256) void spline_kernel(float* __restrict__ p,
    const float* __restrict__ knots, const float* __restrict__ cps,
    const float* __restrict__ stats) {
  __shared__ float ksh[8 * 33], csh[8 * 33];
  int t = threadIdx.x;
  { int f = t >> 5, j = t & 31; ksh[f * 33 + j] = knots[t]; csh[f * 33 + j] = cps[t]; }
  __syncthreads();
  int i = blockIdx.x * 256 + t;
  int f = i & 7;
  float xv = p[i];
  float mn = stats[SOFF_FMIN + f], mx = stats[SOFF_FMAX + f];
  float xn = (xv - mn) / (mx - mn + 1e-6f);
  const float* kn = &ksh[f * 33];
  const float* cp = &csh[f * 33];
  int pcnt = 0;
#pragma unroll
  for (int j = 0; j < 32; ++j) pcnt += (kn[j] <= xn) ? 1 : 0;
  int idx = pcnt - 1;
  idx = idx < 0 ? 0 : (idx > 30 ? 30 : idx);
  float k0v = kn[idx], k1v = kn[idx + 1];
  float tt = (xn - k0v) / (k1v - k0v);
  float val = (1.f - tt) * cp[idx] + tt * cp[idx + 1];
  bool inr = (xn >= kn[0]) && (xn <= kn[31]);
  p[i] = inr ? val : 0.f;
}

// ------------------------------------------- gate-weight Grams (parallel, 88 blocks)
__global__ __launch_bounds__(256) void gateprep_kernel(const float* __restrict__ gw,
    const float* __restrict__ gb, float* __restrict__ stats) {
  int b = blockIdx.x, t = threadIdx.x;
  __shared__ float red[256];
  float s = 0.f;
  if (b < 64) {
    int f1 = b >> 3, f2 = b & 7;
    for (int j = t; j < 1024; j += 256) s += gw[j * 8 + f1] * gw[j * 8 + f2];
  } else if (b < 72) {
    int f = b - 64;
    for (int j = t; j < 1024; j += 256) s += gw[j * 8 + f];
  } else if (b < 80) {
    int f = b - 72;
    for (int j = t; j < 1024; j += 256) s += gb[j] * gw[j * 8 + f];
  } else if (b == 80) {
    for (int j = t; j < 1024; j += 256) s += gb[j];
  } else {
    for (int j = t; j < 1024; j += 256) s += gb[j] * gb[j];
  }
  red[t] = s; __syncthreads();
  for (int off = 128; off > 0; off >>= 1) { if (t < off) red[t] += red[t + off]; __syncthreads(); }
  if (t == 0) {
    float v = red[0];
    if (b < 64) stats[SOFF_G2 + b] = v;
    else if (b < 72) stats[SOFF_G1 + (b - 64)] = v;
    else if (b < 80) stats[SOFF_GB + (b - 72)] = v;
    else if (b == 80) stats[SOFF_SGB] = v;
    else stats[SOFF_QGB] = v;
  }
}

// -------------------------------------- per-s BN stats of h WITHOUT materializing h
__global__ __launch_bounds__(256) void sstats_kernel(const float* __restrict__ tbuf,
                                                     float* __restrict__ stats) {
  int s = blockIdx.x, t = threadIdx.x;
  __shared__ float tv[256];
  __shared__ float red[256];
  __shared__ float T1[8];
  __shared__ float Ms[64];
  int b = t >> 3, f = t & 7;
  tv[t] = tbuf[(b * 1024 + s) * 8 + f];
  __syncthreads();
  red[t] = tv[t]; __syncthreads();
  for (int off = 128; off >= 8; off >>= 1) { if (t < off) red[t] += red[t + off]; __syncthreads(); }
  if (t < 8) T1[t] = red[t];
  if (t < 64) {
    int f1 = t >> 3, f2 = t & 7; float sM = 0.f;
    for (int bb = 0; bb < 32; ++bb) sM += tv[bb * 8 + f1] * tv[bb * 8 + f2];
    Ms[t] = sM;
  }
  __syncthreads();
  if (t == 0) {
    float sh = 0.f, s2 = 0.f;
    for (int ff = 0; ff < 8; ++ff) {
      sh += stats[SOFF_G1 + ff] * T1[ff];
      s2 += 2.f * stats[SOFF_GB + ff] * T1[ff];
    }
    sh += 32.f * stats[SOFF_SGB];
    for (int i = 0; i < 64; ++i) s2 += Ms[i] * stats[SOFF_G2 + i];
    s2 += 32.f * stats[SOFF_QGB];
    float mean = sh / 32768.f;
    float var = s2 / 32768.f - mean * mean;
    stats[SOFF_SMEAN + s] = mean;
    stats[SOFF_SRSTD + s] = rsqrtf(var + 1e-5f);
  }
}

// ---- recompute h row (fp32 gate_w — MUST match sstats' weights), BN-s, GLU, LN
__global__ __launch_bounds__(256) void gluln_kernel(const float* __restrict__ tbuf,
    const float* __restrict__ gw, const float* __restrict__ gb,
    const float* __restrict__ stats, const float* __restrict__ gbng,
    const float* __restrict__ gbnb, const float* __restrict__ lng,
    const float* __restrict__ lnb, unsigned short* __restrict__ gatedb) {
  const int t = threadIdx.x, wave = t >> 6, lane = t & 63;
  for (int rr = 0; rr < 4; ++rr) {
    const int r = blockIdx.x * 16 + wave * 4 + rr;
    const int s = r & 1023;
    float4 tA = *(const float4*)&tbuf[r * 8];
    float4 tB = *(const float4*)&tbuf[r * 8 + 4];
    float smean = stats[SOFF_SMEAN + s], srstd = stats[SOFF_SRSTD + s];
    float k1 = srstd * gbng[s];
    float k0 = gbnb[s] - smean * k1;
    float g[8];
    float sum = 0.f, sq = 0.f;
#pragma unroll
    for (int i = 0; i < 8; ++i) {
      int c = i * 64 + lane;
      float4 wa0 = *(const float4*)&gw[c * 8];
      float4 wa1 = *(const float4*)&gw[c * 8 + 4];
      float4 wb0 = *(const float4*)&gw[(c + 512) * 8];
      float4 wb1 = *(const float4*)&gw[(c + 512) * 8 + 4];
      float ha = tA.x * wa0.x + tA.y * wa0.y + tA.z * wa0.z + tA.w * wa0.w
               + tB.x * wa1.x + tB.y * wa1.y + tB.z * wa1.z + tB.w * wa1.w + gb[c];
      float hb = tA.x * wb0.x + tA.y * wb0.y + tA.z * wb0.z + tA.w * wb0.w
               + tB.x * wb1.x + tB.y * wb1.y + tB.z * wb1.z + tB.w * wb1.w + gb[c + 512];
      ha = ha * k1 + k0;
      hb = hb * k1 + k0;
      float gv = ha / (1.f + __expf(-hb));
      g[i] = gv; sum += gv; sq += gv * gv;
    }
#pragma unroll
    for (int m = 32; m >= 1; m >>= 1) { sum += __shfl_xor(sum, m); sq += __shfl_xor(sq, m); }
    float mean = sum * (1.f / 512.f);
    float rstd = rsqrtf(sq * (1.f / 512.f) - mean * mean + 1e-5f);
#pragma unroll
    for (int i = 0; i < 8; ++i) {
      int c = i * 64 + lane;
      gatedb[(size_t)r * 512 + c] = f2bf((g[i] - mean) * rstd * lng[c] + lnb[c]);
    }
  }
}

// ---------------------------------------------------------------- final elementwise
__global__ __launch_bounds__(256) void final_kernel(const float* __restrict__ x,
    const float* __restrict__ attn, const float* __restrict__ outl,
    const float* __restrict__ stats, const float* __restrict__ ag,
    const float* __restrict__ ab, const float* __restrict__ og,
    const float* __restrict__ ob, float* __restrict__ y) {
  int idx = blockIdx.x * 256 + threadIdx.x;
  int c4 = (idx & 127) * 4;
  float4 xv = ((const float4*)x)[idx];
  float4 av = ((const float4*)attn)[idx];
  float4 ov = ((const float4*)outl)[idx];
  float4 am = *(const float4*)&stats[SOFF_AMEAN + c4];
  float4 ar = *(const float4*)&stats[SOFF_ARSTD + c4];
  float4 om = *(const float4*)&stats[SOFF_OMEAN + c4];
  float4 orr = *(const float4*)&stats[SOFF_ORSTD + c4];
  float4 g1 = *(const float4*)&ag[c4];
  float4 b1 = *(const float4*)&ab[c4];
  float4 g2 = *(const float4*)&og[c4];
  float4 b2 = *(const float4*)&ob[c4];
  float4 o;
  o.x = xv.x + (av.x - am.x) * ar.x * g1.x + b1.x + (ov.x - om.x) * orr.x * g2.x + b2.x;
  o.y = xv.y + (av.y - am.y) * ar.y * g1.y + b1.y + (ov.y - om.y) * orr.y * g2.y + b2.y;
  o.z = xv.z + (av.z - am.z) * ar.z * g1.z + b1.z + (ov.z - om.z) * orr.z * g2.z + b2.z;
  o.w = xv.w + (av.w - am.w) * ar.w * g1.w + b1.w + (ov.w - om.w) * orr.w * g2.w + b2.w;
  ((float4*)y)[idx] = o;
}

extern "C" void kernel_launch(void* const* d_in, const int* in_sizes, int n_in,
                              void* d_out, int out_size, void* d_ws, size_t ws_size,
                              hipStream_t stream) {
  (void)in_sizes; (void)n_in; (void)out_size; (void)ws_size;
  const float* x        = (const float*)d_in[0];
  const float* in_w     = (const float*)d_in[1];
  const float* in_b     = (const float*)d_in[2];
  const float* out_w    = (const float*)d_in[3];
  const float* out_b    = (const float*)d_in[4];
  const float* attn_g   = (const float*)d_in[5];
  const float* attn_bt  = (const float*)d_in[6];
  const float* proj_w   = (const float*)d_in[7];
  const float* proj_b   = (const float*)d_in[8];
  const float* pn_g     = (const float*)d_in[9];
  const float* pn_bt    = (const float*)d_in[10];
  const float* knots    = (const float*)d_in[11];
  const float* cps      = (const float*)d_in[12];
  const float* gate_w   = (const float*)d_in[13];
  const float* gate_b   = (const float*)d_in[14];
  const float* gbn_g    = (const float*)d_in[15];
  const float* gbn_bt   = (const float*)d_in[16];
  const float* ln_g     = (const float*)d_in[17];
  const float* ln_bt    = (const float*)d_in[18];
  const float* outp_w   = (const float*)d_in[19];
  const float* outp_b   = (const float*)d_in[20];
  const float* on_g     = (const float*)d_in[21];
  const float* on_bt    = (const float*)d_in[22];

  float* out = (float*)d_out;
  unsigned short* xb      = (unsigned short*)d_ws;      // 16777216
  unsigned short* qkv_b   = xb + 16777216;              // 50331648
  unsigned short* ctx_b   = qkv_b + 50331648;           // 16777216
  unsigned short* wqkv_b  = ctx_b + 16777216;           // 786432
  unsigned short* wout_b  = wqkv_b + 786432;            // 262144
  unsigned short* woutp_b = wout_b + 262144;            // 262144
  float* proj  = (float*)(woutp_b + 262144);            // 262144 floats
  float* stats = proj + 262144;
  float* part  = stats + SOFF_PART;                     // 4096 floats
  float* partA  = part;                                 // 1024 (atomic col stats attn)
  float* partO  = part + 1024;                          // 1024 (atomic col stats out)
  float* partP  = part + 2048;                          // 1024 (projstats partials)
  float* partMM = part + 3072;                          // 1024 (minmax partials)
  float* attnf = (float*)qkv_b;      // alias: qkv dead after attn3
  unsigned short* gated_b = xb;      // alias: xb dead after qkv GEMM

  zero_kernel<<<dim3(8), dim3(256), 0, stream>>>(part);   // partA+partO
  cvt8_kernel<<<dim3(8192), dim3(256), 0, stream>>>(x, xb);
  cvt8_kernel<<<dim3(384), dim3(256), 0, stream>>>(in_w, wqkv_b);
  cvt8_kernel<<<dim3(128), dim3(256), 0, stream>>>(out_w, wout_b);
  cvt8_kernel<<<dim3(128), dim3(256), 0, stream>>>(outp_w, woutp_b);
  // qkv = x @ in_w^T + in_b -> bf16   (128 m-tiles x 6 n-tiles = 768 blocks)
  gemm256_kernel<6, true, false><<<dim3(768), dim3(512), 0, stream>>>(
      xb, wqkv_b, in_b, qkv_b, nullptr, nullptr, 1536);
  attn3_kernel<<<dim3(1024, 8), dim3(64), 0, stream>>>(qkv_b, ctx_b);
  // attn_lin = ctx @ out_w^T + out_b -> fp32 (+ fused column stats)
  gemm256_kernel<2, false, true><<<dim3(256), dim3(512), 0, stream>>>(
      ctx_b, wout_b, out_b, nullptr, attnf, partA, 512);
  statsfin_kernel<<<dim3(1), dim3(512), 0, stream>>>(partA, stats, SOFF_AMEAN);
  proj_kernel<<<dim3(512), dim3(256), 0, stream>>>(x, proj_w, proj_b, proj);
  projstats_kernel<<<dim3(64), dim3(256), 0, stream>>>(proj, partP);
  projfin_kernel<<<dim3(1), dim3(64), 0, stream>>>(partP, stats);
  bnminmax_kernel<<<dim3(64), dim3(256), 0, stream>>>(proj, stats, pn_g, pn_bt, partMM);
  minmaxfin_kernel<<<dim3(1), dim3(64), 0, stream>>>(partMM, stats);
  spline_kernel<<<dim3(1024), dim3(256), 0, stream>>>(proj, knots, cps, stats);
  gateprep_kernel<<<dim3(88), dim3(256), 0, stream>>>(gate_w, gate_b, stats);
  sstats_kernel<<<dim3(1024), dim3(256), 0, stream>>>(proj, stats);
  gluln_kernel<<<dim3(2048), dim3(256), 0, stream>>>(proj, gate_w, gate_b, stats,
                                                     gbn_g, gbn_bt, ln_g, ln_bt, gated_b);
  // out = gated @ outp_w^T + outp_b -> fp32 (+ fused column stats)
  gemm256_kernel<2, false, true><<<dim3(256), dim3(512), 0, stream>>>(
      gated_b, woutp_b, outp_b, nullptr, out, partO, 512);
  statsfin_kernel<<<dim3(1), dim3(512), 0, stream>>>(partO, stats, SOFF_OMEAN);
  final_kernel<<<dim3(16384), dim3(256), 0, stream>>>(x, attnf, out, stats,
                                                      attn_g, attn_bt, on_g, on_bt, out);
}